// Round 2
// baseline (93.374 us; speedup 1.0000x reference)
//
#include <hip/hip_runtime.h>

#define NN 20000
#define VV 100000
#define CC 5000
#define MM 32
#define KK 2048
#define DD 128

// ---------------- K0: active-community table ----------------
__global__ __launch_bounds__(256) void scatter_active_k(const int* __restrict__ cidx,
                                                        int* __restrict__ active) {
  int k = blockIdx.x * 256 + threadIdx.x;
  if (k < KK) active[cidx[k]] = 1;
}

// ---------------- K1: per-community member embedding ----------------
// memb[c][d] = sum_m (valid ? member_score[c][m] : 0) * cemb[n2c[community2node[c][m]]][d]
// valid = (m < member_num[c]) && active[n2c[member]]
// NOTE: reference gathers community_embeddings by the member's COMMUNITY id.
__global__ __launch_bounds__(128) void member_emb_k(const int* __restrict__ c2n,
    const int* __restrict__ n2c, const float* __restrict__ mscore,
    const int* __restrict__ mnum, const int* __restrict__ active,
    const float* __restrict__ cemb, float* __restrict__ memb) {
  int c = blockIdx.x;
  __shared__ float s_sc[MM];
  __shared__ int s_nc[MM];
  int t = threadIdx.x;  // 0..127 = d
  if (t < MM) {
    int mem = c2n[c * MM + t];
    int nc = n2c[mem];
    bool valid = (t < mnum[c]) && (active[nc] != 0);
    s_nc[t] = nc;
    s_sc[t] = valid ? mscore[c * MM + t] : 0.f;
  }
  __syncthreads();
  float acc = 0.f;
  #pragma unroll
  for (int m = 0; m < MM; ++m) {
    float s = s_sc[m];  // uniform across wave
    if (s != 0.f) acc += s * cemb[(size_t)s_nc[m] * DD + t];
  }
  memb[(size_t)c * DD + t] = acc;
}

// ---------------- K2: pred2 for ALL nodes -> out ----------------
// 128 threads, 32 nodes/block. Per wave: 2 node-groups of 8, each lane owns 2 cols.
__global__ __launch_bounds__(128) void pred2_k(const float* __restrict__ node_emb,
    const float* __restrict__ W3, const float* __restrict__ b3,
    const float* __restrict__ W4, const float* __restrict__ b4v,
    float* __restrict__ out) {
  __shared__ __align__(16) float s_ne[32][DD];  // 16 KB, node rows are contiguous in mem
  int tid = threadIdx.x;
  int n0 = blockIdx.x * 32;
  {
    const float4* src = (const float4*)(node_emb + (size_t)n0 * DD);
    float4* dst = (float4*)&s_ne[0][0];
    #pragma unroll
    for (int p = 0; p < 8; ++p) dst[tid + 128 * p] = src[tid + 128 * p];
  }
  __syncthreads();
  int cl = tid & 31;          // column pair: cols 2cl, 2cl+1
  int grp = (tid >> 5) & 1;   // node subgroup within wave
  int wv = tid >> 6;
  int nbase = wv * 16 + grp * 8;
  int c0 = cl * 2;
  float acc0[8], acc1[8];
  #pragma unroll
  for (int s = 0; s < 8; ++s) { acc0[s] = 0.f; acc1[s] = 0.f; }
  for (int i = 0; i < DD; i += 4) {
    float2 w0 = *(const float2*)&W3[(size_t)(i + 0) * 64 + c0];
    float2 w1 = *(const float2*)&W3[(size_t)(i + 1) * 64 + c0];
    float2 w2 = *(const float2*)&W3[(size_t)(i + 2) * 64 + c0];
    float2 w3 = *(const float2*)&W3[(size_t)(i + 3) * 64 + c0];
    #pragma unroll
    for (int s = 0; s < 8; ++s) {
      float4 ne = *(const float4*)&s_ne[nbase + s][i];
      acc0[s] += ne.x * w0.x + ne.y * w1.x + ne.z * w2.x + ne.w * w3.x;
      acc1[s] += ne.x * w0.y + ne.y * w1.y + ne.z * w2.y + ne.w * w3.y;
    }
  }
  float b3a = b3[c0], b3b = b3[c0 + 1];
  float w4a = W4[c0], w4b = W4[c0 + 1];
  float bias = b4v[0];
  #pragma unroll
  for (int s = 0; s < 8; ++s) {
    float h0 = fmaxf(acc0[s] + b3a, 0.f);
    float h1 = fmaxf(acc1[s] + b3b, 0.f);
    float p = h0 * w4a + h1 * w4b;
    #pragma unroll
    for (int m = 16; m >= 1; m >>= 1) p += __shfl_xor(p, m, 64);
    if (cl == 0) out[n0 + nbase + s] = p + bias;
  }
}

// ---------------- K3: pred1, overwrite out where use ----------------
// 128 threads, 32 nodes/block; thread tile = 8 nodes x 4 cols.
// feat[32][384] staged in LDS, padded to 388 floats (breaks 1536B stride bank alias).
__global__ __launch_bounds__(128) void pred1_k(const float* __restrict__ node_emb,
    const float* __restrict__ cemb, const float* __restrict__ memb,
    const float* __restrict__ W1, const float* __restrict__ b1,
    const float* __restrict__ W2, const float* __restrict__ b2v,
    const int* __restrict__ n2c, const int* __restrict__ active,
    const int* __restrict__ nodes, float* __restrict__ out) {
  __shared__ __align__(16) float s_feat[32][388];  // 49.7 KB
  __shared__ int s_v[32], s_cm[32], s_use[32];
  int tid = threadIdx.x;
  int n0 = blockIdx.x * 32;
  if (tid < 32) {
    int v = nodes[n0 + tid];
    int cm = n2c[v];
    s_v[tid] = v; s_cm[tid] = cm; s_use[tid] = active[cm];
  }
  __syncthreads();
  for (int s = 0; s < 32; ++s) {
    int v = s_v[s], cm = s_cm[s], use = s_use[s];
    s_feat[s][tid]          = node_emb[(size_t)(n0 + s) * DD + tid];
    s_feat[s][DD + tid]     = cemb[(size_t)v * DD + tid];
    s_feat[s][2 * DD + tid] = use ? memb[(size_t)cm * DD + tid] : 0.f;
  }
  __syncthreads();
  int ct = tid & 31, grp = tid >> 5;  // 4 groups x 8 nodes
  int c0 = ct * 4;
  float acc[8][4];
  #pragma unroll
  for (int s = 0; s < 8; ++s)
    #pragma unroll
    for (int c = 0; c < 4; ++c) acc[s][c] = 0.f;
  for (int i = 0; i < 3 * DD; i += 4) {
    float4 w0 = *(const float4*)&W1[(size_t)(i + 0) * DD + c0];
    float4 w1 = *(const float4*)&W1[(size_t)(i + 1) * DD + c0];
    float4 w2 = *(const float4*)&W1[(size_t)(i + 2) * DD + c0];
    float4 w3 = *(const float4*)&W1[(size_t)(i + 3) * DD + c0];
    #pragma unroll
    for (int s = 0; s < 8; ++s) {
      float4 f = *(const float4*)&s_feat[grp * 8 + s][i];
      acc[s][0] += f.x * w0.x + f.y * w1.x + f.z * w2.x + f.w * w3.x;
      acc[s][1] += f.x * w0.y + f.y * w1.y + f.z * w2.y + f.w * w3.y;
      acc[s][2] += f.x * w0.z + f.y * w1.z + f.z * w2.z + f.w * w3.z;
      acc[s][3] += f.x * w0.w + f.y * w1.w + f.z * w2.w + f.w * w3.w;
    }
  }
  float4 bb  = *(const float4*)&b1[c0];
  float4 ww2 = *(const float4*)&W2[c0];
  float bias = b2v[0];
  #pragma unroll
  for (int s = 0; s < 8; ++s) {
    float h0 = fmaxf(acc[s][0] + bb.x, 0.f);
    float h1 = fmaxf(acc[s][1] + bb.y, 0.f);
    float h2 = fmaxf(acc[s][2] + bb.z, 0.f);
    float h3 = fmaxf(acc[s][3] + bb.w, 0.f);
    float p = h0 * ww2.x + h1 * ww2.y + h2 * ww2.z + h3 * ww2.w;
    #pragma unroll
    for (int m = 16; m >= 1; m >>= 1) p += __shfl_xor(p, m, 64);
    if (ct == 0 && s_use[grp * 8 + s]) out[n0 + grp * 8 + s] = p + bias;
  }
}

extern "C" void kernel_launch(void* const* d_in, const int* in_sizes, int n_in,
                              void* d_out, int out_size, void* d_ws, size_t ws_size,
                              hipStream_t stream) {
  const float* node_emb = (const float*)d_in[0];
  const float* mscore   = (const float*)d_in[1];
  const float* cemb     = (const float*)d_in[2];
  const float* W1 = (const float*)d_in[3];
  const float* b1 = (const float*)d_in[4];
  const float* W2 = (const float*)d_in[5];
  const float* b2 = (const float*)d_in[6];
  const float* W3 = (const float*)d_in[7];
  const float* b3 = (const float*)d_in[8];
  const float* W4 = (const float*)d_in[9];
  const float* b4 = (const float*)d_in[10];
  const int* n2c   = (const int*)d_in[11];
  const int* c2n   = (const int*)d_in[12];
  const int* mnum  = (const int*)d_in[13];
  const int* cidx  = (const int*)d_in[14];
  const int* nodes = (const int*)d_in[15];
  float* out = (float*)d_out;

  // workspace layout: active[C] ints at 0; memb[C*D] floats at 32768
  int* active = (int*)d_ws;
  float* memb = (float*)((char*)d_ws + 32768);

  hipMemsetAsync(active, 0, CC * sizeof(int), stream);
  scatter_active_k<<<(KK + 255) / 256, 256, 0, stream>>>(cidx, active);
  member_emb_k<<<CC, 128, 0, stream>>>(c2n, n2c, mscore, mnum, active, cemb, memb);
  pred2_k<<<NN / 32, 128, 0, stream>>>(node_emb, W3, b3, W4, b4, out);
  pred1_k<<<NN / 32, 128, 0, stream>>>(node_emb, cemb, memb, W1, b1, W2, b2,
                                       n2c, active, nodes, out);
}